// Round 4
// baseline (340.616 us; speedup 1.0000x reference)
//
#include <hip/hip_runtime.h>
#include <math.h>

// Problem constants
#define HH 56
#define WW 56
#define NB 32
#define CC 256
#define PIX 3136               // 56*56
#define M_TOT 100352           // 32*3136
#define PADH 58
#define PADW 58
#define ACTQ_BYTES ((size_t)NB*PADH*PADW*CC)   // 27,553,792
#define WQ_BYTES ((size_t)9*CC*CC)             // 589,824
#define SBUF_BYTES ((size_t)M_TOT*CC*2)        // 51,380,224
#define NTILES 392             // M_TOT / 256
#define NJOBS 1568             // NTILES * 4 col-tiles

typedef unsigned int u32;
typedef unsigned long long u64;
typedef int v4i __attribute__((ext_vector_type(4)));

// ---------------------------------------------------------------------------
// Pack weights: per-co mean (double), unbiased std, sw = 2^round(log2 mean|bw|),
// and sign bytes wq[tap][co][ci] in {-1,+1}. Zeroes stat accumulators.
// ---------------------------------------------------------------------------
__global__ __launch_bounds__(256) void pack_weights_i8(
    const float* __restrict__ wt, signed char* __restrict__ wq,
    float* __restrict__ swv,
    long long* __restrict__ sumS, long long* __restrict__ sumSS) {
  int co = blockIdx.x;
  int t  = threadIdx.x;          // = ci
  int lane = t & 63, wid = t >> 6;

  float wv[9];
  const float* wp = wt + ((size_t)co*CC + t)*9;
  double psum = 0.0;
#pragma unroll
  for (int k = 0; k < 9; ++k) { wv[k] = wp[k]; psum += (double)wv[k]; }

  __shared__ double redm[4];
#pragma unroll
  for (int off = 32; off > 0; off >>= 1) psum += __shfl_xor(psum, off);
  if (lane == 0) redm[wid] = psum;
  __syncthreads();
  double mean = (redm[0]+redm[1]+redm[2]+redm[3]) * (1.0/2304.0);

  double pabs = 0.0, psq = 0.0;
#pragma unroll
  for (int k = 0; k < 9; ++k) {
    double d = (double)wv[k] - mean;
    pabs += fabs(d);
    psq  += d*d;
  }
#pragma unroll
  for (int off = 32; off > 0; off >>= 1) {
    pabs += __shfl_xor(pabs, off);
    psq  += __shfl_xor(psq,  off);
  }
  __shared__ double reda[4], redq[4];
  if (lane == 0) { reda[wid] = pabs; redq[wid] = psq; }
  __syncthreads();
  if (t == 0) {
    double sa = reda[0]+reda[1]+reda[2]+reda[3];
    double sq = redq[0]+redq[1]+redq[2]+redq[3];
    double stdv = sqrt(sq / 2303.0);                 // torch unbiased std
    double mabs = (sa * (1.0/2304.0)) / stdv;        // mean|bw|
    swv[co] = (float)exp2(rint(log2(mabs)));         // round half-to-even
    sumS[co]  = 0;
    sumSS[co] = 0;
  }
  // sign bytes: wq[k][co][ci] (B^T layout rows = co, contiguous ci)
#pragma unroll
  for (int k = 0; k < 9; ++k)
    wq[((size_t)k*CC + co)*CC + t] =
        (((double)wv[k] - mean) > 0.0) ? (signed char)1 : (signed char)-1;
}

// ---------------------------------------------------------------------------
// Pack activations: sign(x) -> i8 channel-last padded [n][h+1][w+1][ci].
// Borders pre-zeroed by memset.
// ---------------------------------------------------------------------------
__global__ __launch_bounds__(256) void pack_acts_i8(
    const float* __restrict__ x, signed char* __restrict__ actq) {
  int n = blockIdx.y, tile = blockIdx.x;               // 49 tiles of 64 pl
  int lane = threadIdx.x & 63, cw = threadIdx.x >> 6;  // cw: 64-ci group
  int pl = tile*64 + lane;
  int h = pl / WW, w = pl % WW;
  const float* xp = x + ((size_t)(n*CC + cw*64))*PIX + pl;
  u32 wrd[16];
#pragma unroll
  for (int c16 = 0; c16 < 16; ++c16) {
    u32 v = 0;
#pragma unroll
    for (int b = 0; b < 4; ++b) {
      float f = xp[(size_t)(c16*4 + b)*PIX];
      v |= (f > 0.0f ? 0x01u : 0xFFu) << (8*b);   // +1 / -1 as i8
    }
    wrd[c16] = v;
  }
  signed char* dst = actq + ((size_t)(n*PADH + h+1)*PADW + (w+1))*CC + cw*64;
#pragma unroll
  for (int q = 0; q < 4; ++q)
    ((uint4*)dst)[q] = make_uint4(wrd[4*q], wrd[4*q+1], wrd[4*q+2], wrd[4*q+3]);
}

// ---------------------------------------------------------------------------
// B-stationary implicit-GEMM binary conv, mfma_i32_16x16x64_i8.
// Block: 1024 thr (16 waves), owns a 64-col weight tile in LDS (147 KB,
// loaded once, XOR-swizzled chunk c -> c^(col&7): conflict-free b128 reads).
// K-loop (9 taps x 4 kq) is BARRIER-FREE: A frags stream global->VGPR with
// 1-stage register prefetch; B frags from LDS. Wave = 16 rows x 64 cols.
// Jobs = (col,tile) pairs, contiguous split over 256 blocks (<=2 B reloads).
// ---------------------------------------------------------------------------
template <bool S16>
__global__ __launch_bounds__(1024, 4) void bconv_mfma(
    const signed char* __restrict__ actq, const signed char* __restrict__ wq,
    short* __restrict__ s16out, float* __restrict__ f32out,
    u64* __restrict__ sumS, u64* __restrict__ sumSS) {
  __shared__ signed char Bs[64*2304];       // [col][swizzled k-chunk*16]
  __shared__ long long colS[64], colQ[64];

  int t = threadIdx.x;
  int lane = t & 63;
  int wv = t >> 6;                          // wave 0..15
  int lm = lane & 15, quad = lane >> 4;
  int bx = blockIdx.x;
  int jb = (bx*NJOBS) >> 8, je = ((bx+1)*NJOBS) >> 8;

  if (t < 64) { colS[t] = 0; colQ[t] = 0; }

  int Sacc[4] = {0,0,0,0};
  int Qacc[4] = {0,0,0,0};
  int cur = -1;

  for (int job = jb; job < je; ++job) {
    int col = job / NTILES;
    int tile = job - col*NTILES;
    int n0 = col*64;

    if (col != cur) {
      __syncthreads();                      // all waves done with old B/stats
      if (cur >= 0) {
        // flush stats for old col-tile
#pragma unroll
        for (int j = 0; j < 4; ++j) {
          int S = Sacc[j], Q = Qacc[j];
          S += __shfl_xor(S, 16); S += __shfl_xor(S, 32);
          Q += __shfl_xor(Q, 16); Q += __shfl_xor(Q, 32);
          if (quad == 0) {
            atomicAdd((u64*)&colS[j*16 + lm], (u64)(long long)S);
            atomicAdd((u64*)&colQ[j*16 + lm], (u64)(long long)Q);
          }
          Sacc[j] = 0; Qacc[j] = 0;
        }
        __syncthreads();
        if (t < 64) {
          atomicAdd(&sumS[cur*64 + t], (u64)colS[t]);
          atomicAdd(&sumSS[cur*64 + t], (u64)colQ[t]);
          colS[t] = 0; colQ[t] = 0;
        }
        __syncthreads();
      }
      // load B tile: 64 cols x 2304 B, swizzled
      {
        int c = t >> 4, m = t & 15;
#pragma unroll
        for (int tap = 0; tap < 9; ++tap) {
          int ck = tap*16 + m;
          int ph = ck ^ (c & 7);
          *(uint4*)(Bs + c*2304 + ph*16) =
              *(const uint4*)(wq + (size_t)tap*65536 + (n0 + c)*256 + m*16);
        }
      }
      __syncthreads();
      cur = col;
    }

    // ---- one 256-row M-tile ----
    int P = tile*256 + wv*16 + lm;
    int n_ = P / PIX, pl = P - n_*PIX;
    int h = pl / WW, w = pl - h*WW;
    const signed char* aptr =
        actq + ((size_t)(n_*PADH + h + 1)*PADW + (w + 1))*CC + quad*16;

    v4i acc[4];
#pragma unroll
    for (int j = 0; j < 4; ++j) acc[j] = 0;

    // stage s: tap = s>>2, kq = s&3; A offset relative to aptr
    //   aoff(s) = ((tap/3 - 1)*PADW + (tap%3 - 1))*CC + kq*64
    uint4 areg = *(const uint4*)(aptr + (-PADW - 1)*CC);   // s=0
#pragma unroll 4
    for (int s = 0; s < 36; ++s) {
      int tap = s >> 2, kq = s & 3;
      int ck = tap*16 + kq*4 + quad;
      int ph = ck ^ (lm & 7);
      const signed char* bp = Bs + lm*2304 + ph*16;
      v4i bf0 = *(const v4i*)(bp);
      v4i bf1 = *(const v4i*)(bp + 16*2304);
      v4i bf2 = *(const v4i*)(bp + 32*2304);
      v4i bf3 = *(const v4i*)(bp + 48*2304);
      int sn = (s < 35) ? s + 1 : 35;
      int tn = sn >> 2, kn = sn & 3;
      int anoff = ((tn/3 - 1)*PADW + (tn%3 - 1))*CC + kn*64;
      uint4 anext = *(const uint4*)(aptr + anoff);
      v4i af;
      af.x = (int)areg.x; af.y = (int)areg.y;
      af.z = (int)areg.z; af.w = (int)areg.w;
      acc[0] = __builtin_amdgcn_mfma_i32_16x16x64_i8(af, bf0, acc[0], 0, 0, 0);
      acc[1] = __builtin_amdgcn_mfma_i32_16x16x64_i8(af, bf1, acc[1], 0, 0, 0);
      acc[2] = __builtin_amdgcn_mfma_i32_16x16x64_i8(af, bf2, acc[2], 0, 0, 0);
      acc[3] = __builtin_amdgcn_mfma_i32_16x16x64_i8(af, bf3, acc[3], 0, 0, 0);
      areg = anext;
    }

    // ---- epilogue: store s16/f32 + accumulate stats ----
    int R = tile*256 + wv*16 + quad*4;       // rows R..R+3 (4-aligned; PIX%4==0)
    int nR = R / PIX, plR = R - nR*PIX;
#pragma unroll
    for (int j = 0; j < 4; ++j) {
      int colo = n0 + j*16 + lm;
      v4i a = acc[j];
      size_t idx = ((size_t)nR*CC + colo)*PIX + plR;
      if (S16) {
        int2 pk;
        pk.x = (a.x & 0xFFFF) | (a.y << 16);
        pk.y = (a.z & 0xFFFF) | (a.w << 16);
        *(int2*)(s16out + idx) = pk;
      } else {
        *(float4*)(f32out + idx) =
            make_float4((float)a.x, (float)a.y, (float)a.z, (float)a.w);
      }
      Sacc[j] += a.x + a.y + a.z + a.w;
      Qacc[j] += a.x*a.x + a.y*a.y + a.z*a.z + a.w*a.w;
    }
  }

  // final flush
  __syncthreads();
#pragma unroll
  for (int j = 0; j < 4; ++j) {
    int S = Sacc[j], Q = Qacc[j];
    S += __shfl_xor(S, 16); S += __shfl_xor(S, 32);
    Q += __shfl_xor(Q, 16); Q += __shfl_xor(Q, 32);
    if (quad == 0) {
      atomicAdd((u64*)&colS[j*16 + lm], (u64)(long long)S);
      atomicAdd((u64*)&colQ[j*16 + lm], (u64)(long long)Q);
    }
  }
  __syncthreads();
  if (t < 64) {
    atomicAdd(&sumS[cur*64 + t], (u64)colS[t]);
    atomicAdd(&sumSS[cur*64 + t], (u64)colQ[t]);
  }
}

// ---------------------------------------------------------------------------
// Per-channel BN fold: out = clip(s*A + B)
// ---------------------------------------------------------------------------
__global__ void finalize_stats(
    const long long* __restrict__ sumS, const long long* __restrict__ sumSS,
    const float* __restrict__ swv,
    const float* __restrict__ gamma, const float* __restrict__ beta,
    float* __restrict__ AB) {
  int c = threadIdx.x;
  double mu  = (double)sumS[c]  / (double)M_TOT;
  double var = (double)sumSS[c] / (double)M_TOT - mu*mu;
  double sw  = (double)swv[c];
  double inv = 1.0 / sqrt(sw*sw*var + 1e-5);
  double scale = (double)gamma[c] * sw * inv;
  double shift = (double)beta[c] - scale * mu;
  AB[c]      = (float)scale;
  AB[CC + c] = (float)shift;
}

__global__ __launch_bounds__(256) void bn_apply_s16(
    const short* __restrict__ s, float* __restrict__ out,
    const float* __restrict__ AB, int n8) {
  int i = blockIdx.x*256 + threadIdx.x;
  if (i >= n8) return;
  union { int4 v; short sh[8]; } u;
  u.v = ((const int4*)s)[i];
  int c = ((i*8) / PIX) & (CC-1);   // PIX % 8 == 0 -> c uniform across the 8
  float a = AB[c], b = AB[CC + c];
  float4 o0, o1;
  o0.x = fminf(1.f, fmaxf(-1.f, (float)u.sh[0]*a + b));
  o0.y = fminf(1.f, fmaxf(-1.f, (float)u.sh[1]*a + b));
  o0.z = fminf(1.f, fmaxf(-1.f, (float)u.sh[2]*a + b));
  o0.w = fminf(1.f, fmaxf(-1.f, (float)u.sh[3]*a + b));
  o1.x = fminf(1.f, fmaxf(-1.f, (float)u.sh[4]*a + b));
  o1.y = fminf(1.f, fmaxf(-1.f, (float)u.sh[5]*a + b));
  o1.z = fminf(1.f, fmaxf(-1.f, (float)u.sh[6]*a + b));
  o1.w = fminf(1.f, fmaxf(-1.f, (float)u.sh[7]*a + b));
  ((float4*)out)[2*i]   = o0;
  ((float4*)out)[2*i+1] = o1;
}

__global__ __launch_bounds__(256) void bn_apply_f32(
    float* __restrict__ out, const float* __restrict__ AB, int n4) {
  int i = blockIdx.x*256 + threadIdx.x;
  if (i >= n4) return;
  float4 v = ((float4*)out)[i];
  int c = ((i*4) / PIX) & (CC-1);
  float a = AB[c], b = AB[CC + c];
  v.x = fminf(1.f, fmaxf(-1.f, v.x*a + b));
  v.y = fminf(1.f, fmaxf(-1.f, v.y*a + b));
  v.z = fminf(1.f, fmaxf(-1.f, v.z*a + b));
  v.w = fminf(1.f, fmaxf(-1.f, v.w*a + b));
  ((float4*)out)[i] = v;
}

extern "C" void kernel_launch(void* const* d_in, const int* in_sizes, int n_in,
                              void* d_out, int out_size, void* d_ws, size_t ws_size,
                              hipStream_t stream) {
  (void)in_sizes; (void)n_in; (void)out_size;
  const float* x     = (const float*)d_in[0];
  const float* wt    = (const float*)d_in[1];
  const float* gamma = (const float*)d_in[2];
  const float* beta  = (const float*)d_in[3];
  float* out = (float*)d_out;

  char* ws = (char*)d_ws;
  size_t off = 0;
  signed char* actq = (signed char*)(ws + off);
  off += ACTQ_BYTES;             off = (off + 255) & ~(size_t)255;
  signed char* wq = (signed char*)(ws + off);
  off += WQ_BYTES;               off = (off + 255) & ~(size_t)255;
  float* swv = (float*)(ws + off); off += 1024;
  float* AB  = (float*)(ws + off); off += 2048;
  long long* sumS  = (long long*)(ws + off); off += 2048;
  long long* sumSS = (long long*)(ws + off); off += 2048;
  off = (off + 255) & ~(size_t)255;
  short* sbuf = (short*)(ws + off);
  bool s16 = (ws_size >= off + SBUF_BYTES);

  hipMemsetAsync(actq, 0, ACTQ_BYTES, stream);     // zero padded borders
  pack_weights_i8<<<256, 256, 0, stream>>>(wt, wq, swv, sumS, sumSS);
  pack_acts_i8<<<dim3(49, NB), 256, 0, stream>>>(x, actq);
  if (s16) {
    bconv_mfma<true><<<256, 1024, 0, stream>>>(
        actq, wq, sbuf, nullptr, (u64*)sumS, (u64*)sumSS);
  } else {
    bconv_mfma<false><<<256, 1024, 0, stream>>>(
        actq, wq, nullptr, out, (u64*)sumS, (u64*)sumSS);
  }
  finalize_stats<<<1, 256, 0, stream>>>(sumS, sumSS, swv, gamma, beta, AB);
  if (s16) {
    bn_apply_s16<<<(M_TOT*CC/8 + 255)/256, 256, 0, stream>>>(
        sbuf, out, AB, M_TOT*CC/8);
  } else {
    bn_apply_f32<<<(M_TOT*CC/4 + 255)/256, 256, 0, stream>>>(
        out, AB, M_TOT*CC/4);
  }
}

// Round 5
// 312.129 us; speedup vs baseline: 1.0913x; 1.0913x over previous
//
#include <hip/hip_runtime.h>
#include <math.h>

// Problem constants
#define HH 56
#define WW 56
#define NB 32
#define CC 256
#define PIX 3136               // 56*56
#define M_TOT 100352           // 32*3136
#define PADH 58
#define PADW 58
#define ACTQ_BYTES ((size_t)NB*PADH*PADW*CC)   // 27,553,792
#define WQ_BYTES ((size_t)9*CC*CC)             // 589,824
#define SBUF_BYTES ((size_t)M_TOT*CC*2)        // 51,380,224
#define BM 128
#define BN 128

typedef unsigned int u32;
typedef unsigned long long u64;
typedef int v4i __attribute__((ext_vector_type(4)));

// global_load_lds, width 16 (global -> LDS DMA; dest = wave base + lane*16)
typedef const __attribute__((address_space(1))) unsigned int* as1_u32p;
typedef __attribute__((address_space(3))) unsigned int* as3_u32p;
#define GLOAD_LDS16(g, l) \
  __builtin_amdgcn_global_load_lds((as1_u32p)(g), (as3_u32p)(l), 16, 0, 0)

// ---------------------------------------------------------------------------
// Pack weights: per-co mean (double), unbiased std, sw = 2^round(log2 mean|bw|),
// sign bytes wq[tap][co][ci] in {-1,+1}. Zeroes stat accumulators.
// ---------------------------------------------------------------------------
__global__ __launch_bounds__(256) void pack_weights_i8(
    const float* __restrict__ wt, signed char* __restrict__ wq,
    float* __restrict__ swv,
    long long* __restrict__ sumS, long long* __restrict__ sumSS) {
  int co = blockIdx.x;
  int t  = threadIdx.x;          // = ci
  int lane = t & 63, wid = t >> 6;

  float wv[9];
  const float* wp = wt + ((size_t)co*CC + t)*9;
  double psum = 0.0;
#pragma unroll
  for (int k = 0; k < 9; ++k) { wv[k] = wp[k]; psum += (double)wv[k]; }

  __shared__ double redm[4];
#pragma unroll
  for (int off = 32; off > 0; off >>= 1) psum += __shfl_xor(psum, off);
  if (lane == 0) redm[wid] = psum;
  __syncthreads();
  double mean = (redm[0]+redm[1]+redm[2]+redm[3]) * (1.0/2304.0);

  double pabs = 0.0, psq = 0.0;
#pragma unroll
  for (int k = 0; k < 9; ++k) {
    double d = (double)wv[k] - mean;
    pabs += fabs(d);
    psq  += d*d;
  }
#pragma unroll
  for (int off = 32; off > 0; off >>= 1) {
    pabs += __shfl_xor(pabs, off);
    psq  += __shfl_xor(psq,  off);
  }
  __shared__ double reda[4], redq[4];
  if (lane == 0) { reda[wid] = pabs; redq[wid] = psq; }
  __syncthreads();
  if (t == 0) {
    double sa = reda[0]+reda[1]+reda[2]+reda[3];
    double sq = redq[0]+redq[1]+redq[2]+redq[3];
    double stdv = sqrt(sq / 2303.0);                 // torch unbiased std
    double mabs = (sa * (1.0/2304.0)) / stdv;        // mean|bw|
    swv[co] = (float)exp2(rint(log2(mabs)));         // round half-to-even
    sumS[co]  = 0;
    sumSS[co] = 0;
  }
  // sign bytes: wq[k][co][ci]
#pragma unroll
  for (int k = 0; k < 9; ++k)
    wq[((size_t)k*CC + co)*CC + t] =
        (((double)wv[k] - mean) > 0.0) ? (signed char)1 : (signed char)-1;
}

// ---------------------------------------------------------------------------
// Pack activations: sign(x) -> i8 channel-last padded [n][ph][pw][ci].
// Border cells written as zeros here (memset fused away).
// ---------------------------------------------------------------------------
__global__ __launch_bounds__(256) void pack_acts_i8(
    const float* __restrict__ x, signed char* __restrict__ actq) {
  int n = blockIdx.y, tile = blockIdx.x;               // 53 tiles of 64 padded-pl
  int lane = threadIdx.x & 63, cw = threadIdx.x >> 6;  // cw: 64-ci group
  int pp = tile*64 + lane;
  if (pp >= PADH*PADW) return;
  int ph = pp / PADW, pw = pp - ph*PADW;
  signed char* dst = actq + ((size_t)(n*PADH + ph)*PADW + pw)*CC + cw*64;
  if (ph == 0 || ph == PADH-1 || pw == 0 || pw == PADW-1) {
    uint4 z = make_uint4(0u, 0u, 0u, 0u);
#pragma unroll
    for (int q = 0; q < 4; ++q) ((uint4*)dst)[q] = z;
    return;
  }
  int h = ph - 1, w = pw - 1;
  const float* xp = x + ((size_t)(n*CC + cw*64))*PIX + h*WW + w;
  u32 wrd[16];
#pragma unroll
  for (int c16 = 0; c16 < 16; ++c16) {
    u32 v = 0;
#pragma unroll
    for (int b = 0; b < 4; ++b) {
      float f = xp[(size_t)(c16*4 + b)*PIX];
      v |= (f > 0.0f ? 0x01u : 0xFFu) << (8*b);   // +1 / -1 as i8
    }
    wrd[c16] = v;
  }
#pragma unroll
  for (int q = 0; q < 4; ++q)
    ((uint4*)dst)[q] = make_uint4(wrd[4*q], wrd[4*q+1], wrd[4*q+2], wrd[4*q+3]);
}

// ---------------------------------------------------------------------------
// m97-style double-buffered implicit-GEMM binary conv, mfma_i32_16x16x64_i8.
// Block 128x128, 256 thr (4 waves), wave tile 64x64 (I=J=4: 8 frag loads per
// 16 MFMAs = 512 B LDS/MFMA < 653 B budget -> MFMA-bound). BK=64, 36 stages.
// Staging: global_load_lds width 16 into [row][64B] LDS tiles (m97 layout).
// One barrier per stage. Exact i32; epilogue s16/f32 + per-channel stats.
// ---------------------------------------------------------------------------
template <bool S16>
__global__ __launch_bounds__(256, 3) void bconv_mfma(
    const signed char* __restrict__ actq, const signed char* __restrict__ wq,
    short* __restrict__ s16out, float* __restrict__ f32out,
    u64* __restrict__ sumS, u64* __restrict__ sumSS) {
  __shared__ char lds[32768] __attribute__((aligned(16)));  // 2 x (A 8K | B 8K)
  __shared__ int colS[128], colQ[128];

  int t = threadIdx.x;
  int lane = t & 63, wv = t >> 6;
  int lm = lane & 15, quad = lane >> 4;
  int ar0 = (wv & 1) * 64;         // wave A-row base in tile
  int bc0 = (wv >> 1) * 64;        // wave B-col base in tile
  int Mbase = blockIdx.x * BM;
  int n0 = blockIdx.y * BN;

  if (t < 128) { colS[t] = 0; colQ[t] = 0; }

  // staging: thread t -> rows r, r+64 (A) / cols r, r+64 (B), 16B chunk c16
  int r = t >> 2, c16 = t & 3;
  const signed char *pA0, *pA1;
  {
    int P = Mbase + r;
    int n_ = P / PIX, pl_ = P % PIX, h_ = pl_ / WW, w_ = pl_ % WW;
    pA0 = actq + ((size_t)(n_*PADH + h_+1)*PADW + (w_+1))*CC + c16*16;
    P += 64;
    n_ = P / PIX; pl_ = P % PIX; h_ = pl_ / WW; w_ = pl_ % WW;
    pA1 = actq + ((size_t)(n_*PADH + h_+1)*PADW + (w_+1))*CC + c16*16;
  }
  const signed char* pB0 = wq + (size_t)(n0 + r)*CC + c16*16;
  const signed char* pB1 = pB0 + 64*CC;
  int ldst = t*16;                 // LDS dest: [row][64B] contiguous in t

  v4i acc[4][4];
#pragma unroll
  for (int i = 0; i < 4; ++i)
#pragma unroll
    for (int j = 0; j < 4; ++j) acc[i][j] = 0;

  // stage s: tap = s>>2 (0..8), kq = s&3 (64B k-chunk within tap)
  {
    // prologue: stage 0 into buffer 0   (tap 0: dh=dw=-1, kq=0)
    int aoff = (-PADW - 1)*CC;
    GLOAD_LDS16(pA0 + aoff, lds + ldst);
    GLOAD_LDS16(pA1 + aoff, lds + 4096 + ldst);
    GLOAD_LDS16(pB0, lds + 8192 + ldst);
    GLOAD_LDS16(pB1, lds + 12288 + ldst);
  }

#pragma unroll 1
  for (int s = 0; s < 36; ++s) {
    __syncthreads();               // buf[s&1] DMA drained (vmcnt) + all waves
    if (s < 35) {
      int sn = s + 1;
      int tn = sn >> 2, kn = sn & 3;
      int aoff = ((tn/3 - 1)*PADW + (tn%3 - 1))*CC + kn*64;
      int boff = tn*65536 + kn*64;
      char* nb = (char*)lds + ((sn & 1) << 14);
      GLOAD_LDS16(pA0 + aoff, nb + ldst);
      GLOAD_LDS16(pA1 + aoff, nb + 4096 + ldst);
      GLOAD_LDS16(pB0 + boff, nb + 8192 + ldst);
      GLOAD_LDS16(pB1 + boff, nb + 12288 + ldst);
    }
    const char* cb = (const char*)lds + ((s & 1) << 14);
    v4i af[4], bf[4];
#pragma unroll
    for (int i = 0; i < 4; ++i)
      af[i] = *(const v4i*)(cb + (ar0 + i*16 + lm)*64 + quad*16);
#pragma unroll
    for (int j = 0; j < 4; ++j)
      bf[j] = *(const v4i*)(cb + 8192 + (bc0 + j*16 + lm)*64 + quad*16);
#pragma unroll
    for (int i = 0; i < 4; ++i)
#pragma unroll
      for (int j = 0; j < 4; ++j)
        acc[i][j] = __builtin_amdgcn_mfma_i32_16x16x64_i8(af[i], bf[j],
                                                          acc[i][j], 0, 0, 0);
  }

  // ---- epilogue: store s16/f32 + per-channel stats ----
  int Sl[4] = {0,0,0,0}, Ql[4] = {0,0,0,0};
#pragma unroll
  for (int i = 0; i < 4; ++i) {
    int R = Mbase + ar0 + i*16 + quad*4;   // rows R..R+3 (4-aligned, PIX%4==0)
    int nR = R / PIX, plR = R % PIX;
#pragma unroll
    for (int j = 0; j < 4; ++j) {
      int colo = n0 + bc0 + j*16 + lm;
      v4i a = acc[i][j];
      size_t idx = ((size_t)nR*CC + colo)*PIX + plR;
      if (S16) {
        int2 pk;
        pk.x = (a.x & 0xFFFF) | (a.y << 16);
        pk.y = (a.z & 0xFFFF) | (a.w << 16);
        *(int2*)(s16out + idx) = pk;
      } else {
        *(float4*)(f32out + idx) =
            make_float4((float)a.x, (float)a.y, (float)a.z, (float)a.w);
      }
      Sl[j] += a.x + a.y + a.z + a.w;
      Ql[j] += a.x*a.x + a.y*a.y + a.z*a.z + a.w*a.w;
    }
  }
#pragma unroll
  for (int j = 0; j < 4; ++j) {
    int S = Sl[j], Q = Ql[j];
    S += __shfl_xor(S, 16); S += __shfl_xor(S, 32);   // reduce over quads
    Q += __shfl_xor(Q, 16); Q += __shfl_xor(Q, 32);
    if (quad == 0) {
      atomicAdd(&colS[bc0 + j*16 + lm], S);
      atomicAdd(&colQ[bc0 + j*16 + lm], Q);
    }
  }
  __syncthreads();
  if (t < 128) {
    atomicAdd(&sumS[n0 + t], (u64)(long long)colS[t]);   // 2's-comp wrap ok
    atomicAdd(&sumSS[n0 + t], (u64)(long long)colQ[t]);
  }
}

// ---------------------------------------------------------------------------
// Per-channel BN fold: out = clip(s*A + B)
// ---------------------------------------------------------------------------
__global__ void finalize_stats(
    const long long* __restrict__ sumS, const long long* __restrict__ sumSS,
    const float* __restrict__ swv,
    const float* __restrict__ gamma, const float* __restrict__ beta,
    float* __restrict__ AB) {
  int c = threadIdx.x;
  double mu  = (double)sumS[c]  / (double)M_TOT;
  double var = (double)sumSS[c] / (double)M_TOT - mu*mu;
  double sw  = (double)swv[c];
  double inv = 1.0 / sqrt(sw*sw*var + 1e-5);
  double scale = (double)gamma[c] * sw * inv;
  double shift = (double)beta[c] - scale * mu;
  AB[c]      = (float)scale;
  AB[CC + c] = (float)shift;
}

__global__ __launch_bounds__(256) void bn_apply_s16(
    const short* __restrict__ s, float* __restrict__ out,
    const float* __restrict__ AB, int n8) {
  int i = blockIdx.x*256 + threadIdx.x;
  if (i >= n8) return;
  union { int4 v; short sh[8]; } u;
  u.v = ((const int4*)s)[i];
  int c = ((i*8) / PIX) & (CC-1);   // PIX % 8 == 0 -> c uniform across the 8
  float a = AB[c], b = AB[CC + c];
  float4 o0, o1;
  o0.x = fminf(1.f, fmaxf(-1.f, (float)u.sh[0]*a + b));
  o0.y = fminf(1.f, fmaxf(-1.f, (float)u.sh[1]*a + b));
  o0.z = fminf(1.f, fmaxf(-1.f, (float)u.sh[2]*a + b));
  o0.w = fminf(1.f, fmaxf(-1.f, (float)u.sh[3]*a + b));
  o1.x = fminf(1.f, fmaxf(-1.f, (float)u.sh[4]*a + b));
  o1.y = fminf(1.f, fmaxf(-1.f, (float)u.sh[5]*a + b));
  o1.z = fminf(1.f, fmaxf(-1.f, (float)u.sh[6]*a + b));
  o1.w = fminf(1.f, fmaxf(-1.f, (float)u.sh[7]*a + b));
  ((float4*)out)[2*i]   = o0;
  ((float4*)out)[2*i+1] = o1;
}

__global__ __launch_bounds__(256) void bn_apply_f32(
    float* __restrict__ out, const float* __restrict__ AB, int n4) {
  int i = blockIdx.x*256 + threadIdx.x;
  if (i >= n4) return;
  float4 v = ((float4*)out)[i];
  int c = ((i*4) / PIX) & (CC-1);
  float a = AB[c], b = AB[CC + c];
  v.x = fminf(1.f, fmaxf(-1.f, v.x*a + b));
  v.y = fminf(1.f, fmaxf(-1.f, v.y*a + b));
  v.z = fminf(1.f, fmaxf(-1.f, v.z*a + b));
  v.w = fminf(1.f, fmaxf(-1.f, v.w*a + b));
  ((float4*)out)[i] = v;
}

extern "C" void kernel_launch(void* const* d_in, const int* in_sizes, int n_in,
                              void* d_out, int out_size, void* d_ws, size_t ws_size,
                              hipStream_t stream) {
  (void)in_sizes; (void)n_in; (void)out_size;
  const float* x     = (const float*)d_in[0];
  const float* wt    = (const float*)d_in[1];
  const float* gamma = (const float*)d_in[2];
  const float* beta  = (const float*)d_in[3];
  float* out = (float*)d_out;

  char* ws = (char*)d_ws;
  size_t off = 0;
  signed char* actq = (signed char*)(ws + off);
  off += ACTQ_BYTES;             off = (off + 255) & ~(size_t)255;
  signed char* wq = (signed char*)(ws + off);
  off += WQ_BYTES;               off = (off + 255) & ~(size_t)255;
  float* swv = (float*)(ws + off); off += 1024;
  float* AB  = (float*)(ws + off); off += 2048;
  long long* sumS  = (long long*)(ws + off); off += 2048;
  long long* sumSS = (long long*)(ws + off); off += 2048;
  off = (off + 255) & ~(size_t)255;
  short* sbuf = (short*)(ws + off);
  bool s16 = (ws_size >= off + SBUF_BYTES);

  pack_weights_i8<<<256, 256, 0, stream>>>(wt, wq, swv, sumS, sumSS);
  pack_acts_i8<<<dim3(53, NB), 256, 0, stream>>>(x, actq);  // borders zeroed here
  if (s16) {
    bconv_mfma<true><<<dim3(M_TOT/BM, CC/BN), 256, 0, stream>>>(
        actq, wq, sbuf, nullptr, (u64*)sumS, (u64*)sumSS);
  } else {
    bconv_mfma<false><<<dim3(M_TOT/BM, CC/BN), 256, 0, stream>>>(
        actq, wq, nullptr, out, (u64*)sumS, (u64*)sumSS);
  }
  finalize_stats<<<1, 256, 0, stream>>>(sumS, sumSS, swv, gamma, beta, AB);
  if (s16) {
    bn_apply_s16<<<(M_TOT*CC/8 + 255)/256, 256, 0, stream>>>(
        sbuf, out, AB, M_TOT*CC/8);
  } else {
    bn_apply_f32<<<(M_TOT*CC/4 + 255)/256, 256, 0, stream>>>(
        out, AB, M_TOT*CC/4);
  }
}